// Round 9
// baseline (187.317 us; speedup 1.0000x reference)
//
#include <hip/hip_runtime.h>

typedef __bf16 bf16x8 __attribute__((ext_vector_type(8)));
typedef float f32x4 __attribute__((ext_vector_type(4)));
typedef float f32x16 __attribute__((ext_vector_type(16)));
typedef unsigned int u32x4 __attribute__((ext_vector_type(4)));

__device__ inline unsigned short f2bf(float f) {
    unsigned int x = __builtin_bit_cast(unsigned int, f);
    x += 0x7fff + ((x >> 16) & 1);   // RNE; inputs finite
    return (unsigned short)(x >> 16);
}

// async global->LDS, 16B per lane; LDS dest = wave-uniform base + lane*16
__device__ __forceinline__ void gl_lds16(const unsigned short* g, unsigned short* l)
{
    __builtin_amdgcn_global_load_lds(
        (const __attribute__((address_space(1))) void*)g,
        (__attribute__((address_space(3))) void*)l, 16, 0, 0);
}

// ---------------------------------------------------------------------------
// Fused prep: blocks [0,2048): x fp32 -> xb bf16 (8 elems/thread).
// Blocks [2048,2816): Wq/Wk/Wv fp32 [k][n] -> wqkvT bf16 [n][k] (64x64 tiles).
// ---------------------------------------------------------------------------
__global__ __launch_bounds__(256)
void prep(const float* __restrict__ x, unsigned short* __restrict__ xb,
          const float* __restrict__ Wq, const float* __restrict__ Wk,
          const float* __restrict__ Wv, unsigned short* __restrict__ wT)
{
    __shared__ unsigned short T[64][72];
    if (blockIdx.x < 2048) {
        const size_t i = ((size_t)blockIdx.x * 256 + threadIdx.x) * 8;
        float4 a = *reinterpret_cast<const float4*>(x + i);
        float4 b = *reinterpret_cast<const float4*>(x + i + 4);
        unsigned short t[8] = { f2bf(a.x), f2bf(a.y), f2bf(a.z), f2bf(a.w),
                                f2bf(b.x), f2bf(b.y), f2bf(b.z), f2bf(b.w) };
        *reinterpret_cast<uint4*>(xb + i) = *reinterpret_cast<uint4*>(t);
        return;
    }
    const int blk = blockIdx.x - 2048;
    const int z = blk >> 8, within = blk & 255;
    const float* W = (z == 0) ? Wq : (z == 1) ? Wk : Wv;
    unsigned short* dstBase = wT + (size_t)z * 1024 * 1024;
    const int k0 = (within >> 4) * 64, n0 = (within & 15) * 64;
    const int r = threadIdx.x >> 2, c0 = (threadIdx.x & 3) * 16;
    const float* src = W + (size_t)(k0 + r) * 1024 + n0 + c0;
    #pragma unroll
    for (int j = 0; j < 16; j += 4) {
        float4 f = *reinterpret_cast<const float4*>(src + j);
        T[r][c0 + j]     = f2bf(f.x);
        T[r][c0 + j + 1] = f2bf(f.y);
        T[r][c0 + j + 2] = f2bf(f.z);
        T[r][c0 + j + 3] = f2bf(f.w);
    }
    __syncthreads();
    unsigned short* dst = dstBase + (size_t)(n0 + r) * 1024 + k0 + c0;
    #pragma unroll
    for (int h = 0; h < 2; ++h) {
        unsigned short t8[8];
        #pragma unroll
        for (int j = 0; j < 8; ++j) t8[j] = T[c0 + h * 8 + j][r];
        *reinterpret_cast<uint4*>(dst + h * 8) = *reinterpret_cast<uint4*>(t8);
    }
}

// ---------------------------------------------------------------------------
// gemm8p (R8-verified): QKV projection, 2-phase pipeline. BM=128 BN=192
// BK=64, grid 32x16 = 512 blocks = 2/CU, 8 waves (2Mx4N), acc[4][3].
// Per K-tile: issue 5 gl_lds for t+1 -> compute t -> vmcnt(0) + s_barrier.
// XOR-swizzled LDS reads via pre-swizzled gl_lds source.
// ---------------------------------------------------------------------------
__global__ __launch_bounds__(512, 4)
void gemm8p(const unsigned short* __restrict__ A,
            const unsigned short* __restrict__ BT,
            unsigned short* __restrict__ qb,
            unsigned short* __restrict__ kb,
            unsigned short* __restrict__ vT)
{
    __shared__ unsigned short As[2][128 * 64];   // 2 x 16 KB
    __shared__ unsigned short Bs[2][192 * 64];   // 2 x 24 KB

    const int tid  = threadIdx.x;
    const int wave = tid >> 6, lane = tid & 63;
    const int quad = lane >> 4, l16 = lane & 15;
    const int wm = wave >> 2, wn = wave & 3;     // 2 x 4 wave grid
    const int mBase = blockIdx.y * 128, nBase = blockIdx.x * 192;

    f32x4 acc[4][3] = {};

    const int arow = tid >> 3;                   // row-within-64
    const int u8   = (tid & 7) ^ (arow & 7);     // logical 16B unit 0..7
    const int rx   = l16 & 7;                    // read-side row&7

    auto stage = [&](int kb0, int buf) {         // exactly 5 gl_lds per thread
        #pragma unroll
        for (int i = 0; i < 2; ++i)
            gl_lds16(A + (size_t)(mBase + i * 64 + arow) * 1024 + kb0 + u8 * 8,
                     &As[buf][(i * 512 + wave * 64) * 8]);
        #pragma unroll
        for (int i = 0; i < 3; ++i)
            gl_lds16(BT + (size_t)(nBase + i * 64 + arow) * 1024 + kb0 + u8 * 8,
                     &Bs[buf][(i * 512 + wave * 64) * 8]);
    };

    stage(0, 0);
    __syncthreads();                             // tile 0 landed (full drain, once)

    for (int t = 0; t < 16; ++t) {
        const int buf = t & 1;
        if (t + 1 < 16)
            stage((t + 1) * 64, buf ^ 1);        // issue-early; drains at bottom

        #pragma unroll
        for (int kh = 0; kh < 2; ++kh) {
            bf16x8 af[4], bf[3];
            #pragma unroll
            for (int mr = 0; mr < 4; ++mr) {
                const int row = wm * 64 + mr * 16 + l16;
                af[mr] = *reinterpret_cast<const bf16x8*>(
                    &As[buf][row * 64 + (((kh * 4 + quad) ^ rx) * 8)]);
            }
            #pragma unroll
            for (int nr = 0; nr < 3; ++nr) {
                const int row = wn * 48 + nr * 16 + l16;
                bf[nr] = *reinterpret_cast<const bf16x8*>(
                    &Bs[buf][row * 64 + (((kh * 4 + quad) ^ rx) * 8)]);
            }
            #pragma unroll
            for (int mr = 0; mr < 4; ++mr)
                #pragma unroll
                for (int nr = 0; nr < 3; ++nr)
                    acc[mr][nr] = __builtin_amdgcn_mfma_f32_16x16x32_bf16(
                        af[mr], bf[nr], acc[mr][nr], 0, 0, 0);
        }

        if (t + 1 < 16) {
            asm volatile("s_waitcnt vmcnt(0)" ::: "memory");  // t+1 landed (had
            __builtin_amdgcn_s_barrier();                     // full compute to fly)
        }
    }

    // ---- epilogue: q/k normal, v transposed (boundaries are frag-aligned)
    #pragma unroll
    for (int mr = 0; mr < 4; ++mr) {
        const int row0 = mBase + wm * 64 + mr * 16 + quad * 4;
        #pragma unroll
        for (int nr = 0; nr < 3; ++nr) {
            const int col = nBase + wn * 48 + nr * 16 + l16;
            if (col < 1024) {
                #pragma unroll
                for (int i = 0; i < 4; ++i)
                    qb[(size_t)(row0 + i) * 1024 + col] = f2bf(acc[mr][nr][i]);
            } else if (col < 2048) {
                #pragma unroll
                for (int i = 0; i < 4; ++i)
                    kb[(size_t)(row0 + i) * 1024 + col - 1024] = f2bf(acc[mr][nr][i]);
            } else {
                unsigned short t4[4] = { f2bf(acc[mr][nr][0]), f2bf(acc[mr][nr][1]),
                                         f2bf(acc[mr][nr][2]), f2bf(acc[mr][nr][3]) };
                *reinterpret_cast<uint2*>(&vT[(size_t)(col - 2048) * 4096 + row0]) =
                    *reinterpret_cast<uint2*>(t4);
            }
        }
    }
}

// ---------------------------------------------------------------------------
// gemm2f: out-projection out = ctx @ Wo + bias, with Wo transpose+convert
// FUSED into the B-staging (replaces the separate wconv kernel; 5->4
// kernels). BM=BN=128, BK=64, grid 8x32 = 256 blocks, 256 threads (4 waves
// 2x2, wave tile 64x64, acc[4][4]). A (ctx bf16): gl_lds16 with the proven
// XOR-swizzled source. B (Wo fp32 [k][n]): reg-stage 8 float4/thread,
// convert, ds_write_b16 transposed into padded Bs[n][72] (write stride
// 144B and read stride 144B are both 2 lanes/bank -> free). 2-phase
// pipeline: issue A-DMA + B-global loads for t+1 -> compute t -> write
// B(t+1) -> drain -> barrier. LDS 68KB -> 2 blocks/CU.
// WAR safety: Bs[buf^1] written at iter-t bottom was last read in iter
// t-1's compute, one full barrier earlier; lgkmcnt(0) before the barrier
// makes the writes visible to iter t+1's reads.
// ---------------------------------------------------------------------------
__global__ __launch_bounds__(256, 2)
void gemm2f(const unsigned short* __restrict__ A,   // ctx bf16 [4096][1024]
            const float* __restrict__ Wo,           // fp32 [1024][1024]
            float* __restrict__ out,
            const float* __restrict__ bias)
{
    __shared__ unsigned short As[2][128 * 64];   // 2 x 16 KB, swizzled
    __shared__ unsigned short Bs[2][128 * 72];   // 2 x 18 KB, [n][k] padded

    const int tid = threadIdx.x;
    const int wave = tid >> 6, lane = tid & 63, quad = lane >> 4, l16 = lane & 15;
    const int wm = wave >> 1, wn = wave & 1;
    const int mBase = blockIdx.y * 128, nBase = blockIdx.x * 128;

    f32x4 acc[4][4] = {};

    // A staging: slot s = i*256 + tid -> row r = i*32 + (tid>>3), pu = tid&7;
    // source fetches logical unit u = pu ^ (r&7) (i*32 vanishes mod 8).
    const int arow = tid >> 3;                   // 0..31
    const int u8   = (tid & 7) ^ (arow & 7);
    const int rx   = l16 & 7;

    auto stageA = [&](int kb0, int buf) {        // exactly 4 gl_lds per thread
        #pragma unroll
        for (int i = 0; i < 4; ++i)
            gl_lds16(A + (size_t)(mBase + i * 32 + arow) * 1024 + kb0 + u8 * 8,
                     &As[buf][(i * 256 + tid) * 8]);
    };

    // B staging: thread covers Wo row kr, cols c0+j*16 .. +3 (8 float4).
    const int kr = tid >> 2;                     // 0..63
    const int c0 = (tid & 3) * 4;
    float4 breg[8];

    auto loadB = [&](int kb0) {
        #pragma unroll
        for (int j = 0; j < 8; ++j)
            breg[j] = *reinterpret_cast<const float4*>(
                &Wo[(size_t)(kb0 + kr) * 1024 + nBase + c0 + j * 16]);
    };
    auto writeB = [&](int buf) {                 // transpose: Bs[n][kr]
        #pragma unroll
        for (int j = 0; j < 8; ++j) {
            const int c = c0 + j * 16;
            Bs[buf][(c + 0) * 72 + kr] = f2bf(breg[j].x);
            Bs[buf][(c + 1) * 72 + kr] = f2bf(breg[j].y);
            Bs[buf][(c + 2) * 72 + kr] = f2bf(breg[j].z);
            Bs[buf][(c + 3) * 72 + kr] = f2bf(breg[j].w);
        }
    };

    loadB(0);
    stageA(0, 0);
    writeB(0);                                   // breg waits inserted by compiler
    __syncthreads();                             // A DMA + B writes visible

    for (int t = 0; t < 16; ++t) {
        const int buf = t & 1;
        if (t + 1 < 16) {
            stageA((t + 1) * 64, buf ^ 1);       // A DMA flies over compute
            loadB((t + 1) * 64);                 // B loads fly over compute
        }

        #pragma unroll
        for (int kh = 0; kh < 2; ++kh) {
            bf16x8 af[4], bf[4];
            #pragma unroll
            for (int mr = 0; mr < 4; ++mr) {
                const int row = wm * 64 + mr * 16 + l16;
                af[mr] = *reinterpret_cast<const bf16x8*>(
                    &As[buf][row * 64 + (((kh * 4 + quad) ^ rx) * 8)]);
            }
            #pragma unroll
            for (int nr = 0; nr < 4; ++nr) {
                const int row = wn * 64 + nr * 16 + l16;
                bf[nr] = *reinterpret_cast<const bf16x8*>(
                    &Bs[buf][row * 72 + kh * 32 + quad * 8]);
            }
            #pragma unroll
            for (int mr = 0; mr < 4; ++mr)
                #pragma unroll
                for (int nr = 0; nr < 4; ++nr)
                    acc[mr][nr] = __builtin_amdgcn_mfma_f32_16x16x32_bf16(
                        af[mr], bf[nr], acc[mr][nr], 0, 0, 0);
        }

        if (t + 1 < 16) {
            writeB(buf ^ 1);                     // loads had whole compute to land
            asm volatile("s_waitcnt vmcnt(0) lgkmcnt(0)" ::: "memory");
            __builtin_amdgcn_s_barrier();
        }
    }

    // ---- epilogue: fp32 out + bias
    #pragma unroll
    for (int mr = 0; mr < 4; ++mr) {
        const int row0 = mBase + wm * 64 + mr * 16 + quad * 4;
        #pragma unroll
        for (int nr = 0; nr < 4; ++nr) {
            const int col = nBase + wn * 64 + nr * 16 + l16;
            const float ba = bias[col];
            #pragma unroll
            for (int i = 0; i < 4; ++i)
                out[(size_t)(row0 + i) * 1024 + col] = acc[mr][nr][i] + ba;
        }
    }
}

// ---------------------------------------------------------------------------
// attn11 (R6-verified): swapped-QK^T 32x32x16 flash attention; on shared
// iterations tiles A and B are fused into one straight-line block so their
// independent chains interleave. In-register softmax (cvt_pk + permlane),
// XOR-swizzled K/V staging, 3-buffer counted-vmcnt staging, triangle fold,
// LDS partial-combine epilogue.
// ---------------------------------------------------------------------------
__global__ __launch_bounds__(256, 2)
void attn11(const unsigned short* __restrict__ q,
            const unsigned short* __restrict__ k,
            const unsigned short* __restrict__ vT,
            unsigned short* __restrict__ ctx)
{
    __shared__ unsigned short Ks[3][64 * 64];  // [buf][key][d], 16B units XOR-swizzled
    __shared__ unsigned short Vs[3][64 * 64];  // [buf][d][key], 16B units XOR-swizzled
    __shared__ float Lt[8 * 64];               // [wave*2+tile][lane] l partials

    const int tid  = threadIdx.x;
    const int wave = tid >> 6, lane = tid & 63;
    const int q32 = lane & 31, hi = lane >> 5;
    const int slice = wave & 1;                // 32-row q slice within 64-row macro tile
    const int ks    = wave >> 1;               // 32-key subtile within 64-key staged tile
    const int j  = blockIdx.x;                 // 0..15 pair index
    const int bh = blockIdx.y;
    const int b = bh >> 4, h = bh & 15;
    const int tokBase = b * 2048;
    const int colBase = h * 64;
    const int qtA = 31 - j, qtB = j;
    const int qloA = qtA * 64 + slice * 32;    // local (per-batch) q-row base of this wave
    const int qloB = qtB * 64 + slice * 32;

    // Q fragments (QK^T B-operand: lane col q = lane&31, d = c*16 + hi*8 + 0..7)
    bf16x8 aqA[4], aqB[4];
    {
        const unsigned short* ra = q + (size_t)(tokBase + qloA + q32) * 1024 + colBase + hi * 8;
        const unsigned short* rb = q + (size_t)(tokBase + qloB + q32) * 1024 + colBase + hi * 8;
        #pragma unroll
        for (int c = 0; c < 4; ++c) {
            aqA[c] = *reinterpret_cast<const bf16x8*>(ra + c * 16);
            aqB[c] = *reinterpret_cast<const bf16x8*>(rb + c * 16);
        }
    }
    // Pin Q here: its scoreboard wait lands pre-loop, so in-loop vmcnt
    // immediates count only staging loads.
    #pragma unroll
    for (int c = 0; c < 4; ++c)
        asm volatile("" :: "v"(aqA[c]), "v"(aqB[c]));

    f32x16 oA[2] = {}, oB[2] = {};             // [d-half], 32q x 32d each
    float lsA = 0.0f, lsB = 0.0f;

    // Staging: K tile = 64 key-rows x 64 d (128B rows, 8 x 16B units);
    // V tile = 64 d-rows x 64 keys. Linear LDS dest (slot s = r*8 + pu),
    // source pre-swizzled so content at unit pu is logical unit pu ^ (r&7).
    const int s0 = (wave * 2 + 0) * 64 + lane;
    const int s1 = (wave * 2 + 1) * 64 + lane;
    const int r0 = s0 >> 3, sw0 = (s0 & 7) ^ (r0 & 7);
    const int r1 = s1 >> 3, sw1 = (s1 & 7) ^ (r1 & 7);
    const size_t kOff0 = (size_t)r0 * 1024 + colBase + sw0 * 8;
    const size_t kOff1 = (size_t)r1 * 1024 + colBase + sw1 * 8;
    const size_t vOff0 = (size_t)(colBase + r0) * 4096 + sw0 * 8;
    const size_t vOff1 = (size_t)(colBase + r1) * 4096 + sw1 * 8;

    auto stage = [&](int tok0, int buf) {      // exactly 4 VMEM loads per wave
        gl_lds16(k  + (size_t)tok0 * 1024 + kOff0, &Ks[buf][(wave * 2 + 0) * 512]);
        gl_lds16(k  + (size_t)tok0 * 1024 + kOff1, &Ks[buf][(wave * 2 + 1) * 512]);
        gl_lds16(vT + vOff0 + tok0,                &Vs[buf][(wave * 2 + 0) * 512]);
        gl_lds16(vT + vOff1 + tok0,                &Vs[buf][(wave * 2 + 1) * 512]);
    };

    bf16x8 ak[4];       // K frags (shared by tiles A and B)
    bf16x8 bv[2][2];    // V frags [k-chunk][d-half] (shared by A and B)

    const int nkt = qtA + 1;                   // 64-key tiles; >= 17 always
    stage(tokBase, 0);                         // prologue: 2 tiles in flight
    stage(tokBase + 64, 1);

    int cur = 0;                               // buffer holding tile kt
    const int krowK = ks * 32 + q32;           // K-frag LDS row for this wave
    for (int kt = 0; kt < nkt; ++kt) {
        // retire tile kt's 4 loads; leave tile kt+1's 4 in flight
        if (kt + 1 < nkt) asm volatile("s_waitcnt vmcnt(4)" ::: "memory");
        else              asm volatile("s_waitcnt vmcnt(0)" ::: "memory");
        __builtin_amdgcn_s_barrier();
        asm volatile("" ::: "memory");

        const int stg = (cur == 0) ? 2 : cur - 1;        // (cur+2)%3
        if (kt + 2 < nkt)
            stage(tokBase + (kt + 2) * 64, stg);         // lands ~2 iters out

        const unsigned short* KsB = Ks[cur];
        const unsigned short* VsB = Vs[cur];
        #pragma unroll
        for (int c = 0; c < 4; ++c) {
            const int u = c * 2 + hi;
            ak[c] = *reinterpret_cast<const bf16x8*>(
                &KsB[krowK * 64 + ((u ^ (krowK & 7)) * 8)]);
        }
        #pragma unroll
        for (int kc = 0; kc < 2; ++kc)
            #pragma unroll
            for (int dh = 0; dh < 2; ++dh) {
                const int vrow = dh * 32 + q32;
                const int u = ks * 4 + kc * 2 + hi;
                bv[kc][dh] = *reinterpret_cast<const bf16x8*>(
                    &VsB[vrow * 64 + ((u ^ (vrow & 7)) * 8)]);
            }

        const int klo = kt * 64 + ks * 32;
        const bool dB = (klo <= qloB + 31);
        const bool dA = (klo <= qloA + 31);

        if (dB) {
            // ---- fused A+B (shared iter): one straight-line block ----
            f32x16 scA = (f32x16)0.0f, scB = (f32x16)0.0f;
            #pragma unroll
            for (int c = 0; c < 4; ++c) {
                scA = __builtin_amdgcn_mfma_f32_32x32x16_bf16(ak[c], aqA[c], scA, 0, 0, 0);
                scB = __builtin_amdgcn_mfma_f32_32x32x16_bf16(ak[c], aqB[c], scB, 0, 0, 0);
            }
            float pA[16], pB[16];
            #pragma unroll
            for (int r = 0; r < 16; ++r) {
                pA[r] = __expf(scA[r] * 0.125f);
                pB[r] = __expf(scB[r] * 0.125f);
            }
            if (klo + 31 > qloB) {                       // diagB only (diagA impossible)
                #pragma unroll
                for (int r = 0; r < 16; ++r) {
                    const int krow = (r & 3) + 8 * (r >> 2) + 4 * hi;
                    if (klo + krow > qloB + q32) pB[r] = 0.0f;
                }
            }
            #pragma unroll
            for (int r = 0; r < 16; ++r) { lsA += pA[r]; lsB += pB[r]; }
            unsigned int pkA[8], pkB[8];
            #pragma unroll
            for (int i = 0; i < 8; ++i) {
                asm("v_cvt_pk_bf16_f32 %0, %1, %2"
                    : "=v"(pkA[i]) : "v"(pA[2 * i]), "v"(pA[2 * i + 1]));
                asm("v_cvt_pk_bf16_f32 %0, %1, %2"
                    : "=v"(pkB[i]) : "v"(pB[2 * i]), "v"(pB[2 * i + 1]));
            }
            #pragma unroll
            for (int kc = 0; kc < 2; ++kc) {
                unsigned int xa0 = pkA[kc * 4 + 0], ya0 = pkA[kc * 4 + 2];
                unsigned int xa1 = pkA[kc * 4 + 1], ya1 = pkA[kc * 4 + 3];
                unsigned int xb0 = pkB[kc * 4 + 0], yb0 = pkB[kc * 4 + 2];
                unsigned int xb1 = pkB[kc * 4 + 1], yb1 = pkB[kc * 4 + 3];
                asm("v_permlane32_swap_b32 %0, %1" : "+v"(xa0), "+v"(ya0));
                asm("v_permlane32_swap_b32 %0, %1" : "+v"(xa1), "+v"(ya1));
                asm("v_permlane32_swap_b32 %0, %1" : "+v"(xb0), "+v"(yb0));
                asm("v_permlane32_swap_b32 %0, %1" : "+v"(xb1), "+v"(yb1));
                const u32x4 wa = { xa0, xa1, ya0, ya1 };
                const u32x4 wb = { xb0, xb1, yb0, yb1 };
                const bf16x8 paA = __builtin_bit_cast(bf16x8, wa);
                const bf16x8 paB = __builtin_bit_cast(bf16x8, wb);
                #pragma unroll
                for (int dh = 0; dh < 2; ++dh) {
                    oA[dh] = __builtin_amdgcn_mfma_f32_32x32x16_bf16(paA, bv[kc][dh], oA[dh], 0, 0, 0);
                    oB[dh] = __builtin_amdgcn_mfma_f32_32x32x16_bf16(paB, bv[kc][dh], oB[dh], 0, 0, 0);
                }
            }
        } else if (dA) {
            // ---- A only ----
            f32x16 sc = (f32x16)0.0f;
            #pragma unroll
            for (int c = 0; c < 4; ++c)
                sc = __builtin_amdgcn_mfma_f32_32x32x16_bf16(ak[c], aqA[c], sc, 0, 0, 0);
            float p[16];
            #pragma unroll
            for (int r = 0; r < 16; ++r) p[r] = __expf(sc[r] * 0.125f);
            if (klo + 31 > qloA) {                       // diagonal block: causal mask
                #pragma unroll
                for (int r = 0; r < 16; ++r) {
                    const int krow = (r & 3) + 8 * (r >> 2) + 4 * hi;
                    if (klo + krow > qloA + q32) p[r] = 0.0f;
                }
            }
            #pragma unroll
            for (int r = 0; r < 16; ++r) lsA += p[r];
            unsigned int pk[8];
            #pragma unroll
            for (int i = 0; i < 8; ++i)
                asm("v_cvt_pk_bf16_f32 %0, %1, %2"
                    : "=v"(pk[i]) : "v"(p[2 * i]), "v"(p[2 * i + 1]));
            #pragma unroll
            for (int kc = 0; kc < 2; ++kc) {
                unsigned int x0 = pk[kc * 4 + 0], y0 = pk[kc * 4 + 2];
                unsigned int x1 = pk[kc * 4 + 1], y1 = pk[kc * 4 + 3];
                asm("v_permlane32_swap_b32 %0, %1" : "+v"(x0), "+v"(y0));
                asm("v_permlane32_swap_b32 %0, %1" : "+v"(x1), "+v"(y1));
                const u32x4 wv = { x0, x1, y0, y1 };
                const bf16x8 pa = __builtin_bit_cast(bf16x8, wv);
                #pragma unroll
                for (int dh = 0; dh < 2; ++dh)
                    oA[dh] = __builtin_amdgcn_mfma_f32_32x32x16_bf16(pa, bv[kc][dh], oA[dh], 0, 0, 0);
            }
        }
        cur = (cur == 2) ? 0 : cur + 1;
    }

    // ---- epilogue: combine the two k-subtile partials per q-slice, normalize
    float* Obuf = reinterpret_cast<float*>(&Ks[0][0]);   // 2 slots x 8KB (overlay)

    __syncthreads();                           // all compute reads done; overlay safe
    Lt[(wave * 2 + 0) * 64 + lane] = lsA;
    Lt[(wave * 2 + 1) * 64 + lane] = lsB;

    auto writePartial = [&](const f32x16 (&o)[2]) {
        float* slot = Obuf + slice * 2048;
        #pragma unroll
        for (int r = 0; r < 16; ++r) {
            const int row = (r & 3) + 8 * (r >> 2) + 4 * hi;
            #pragma unroll
            for (int dh = 0; dh < 2; ++dh)
                slot[row * 64 + dh * 32 + q32] = o[dh][r];
        }
    };
    auto finalize = [&](int t, int qt, const f32x16 (&o)[2]) {
        const float lf = Lt[(slice * 2 + t) * 64 + q32]
                       + Lt[(slice * 2 + t) * 64 + 32 + q32]
                       + Lt[((slice + 2) * 2 + t) * 64 + q32]
                       + Lt[((slice + 2) * 2 + t) * 64 + 32 + q32];
        const float inv = 1.0f / lf;
        const float* slot = Obuf + slice * 2048;
        #pragma unroll
        for (int r = 0; r < 16; ++r) {
            const int row = (r & 3) + 8 * (r >> 2) + 4 * hi;
            const float invr = __shfl(inv, row);
            const size_t gr = (size_t)(tokBase + qt * 64 + slice * 32 + row) * 1024 + colBase;
            #pragma unroll
            for (int dh = 0; dh < 2; ++dh)
                ctx[gr + dh * 32 + q32] =
                    f2bf((o[dh][r] + slot[row * 64 + dh * 32 + q32]) * invr);
        }
    };

    if (ks == 1) writePartial(oA);             // waves 2,3 publish A partials
    __syncthreads();
    if (ks == 0) finalize(0, qtA, oA);         // waves 0,1 finalize tile A
    __syncthreads();
    if (ks == 0) writePartial(oB);             // waves 0,1 publish B partials
    __syncthreads();
    if (ks == 1) finalize(1, qtB, oB);         // waves 2,3 finalize tile B
}

// ---------------------------------------------------------------------------
extern "C" void kernel_launch(void* const* d_in, const int* in_sizes, int n_in,
                              void* d_out, int out_size, void* d_ws, size_t ws_size,
                              hipStream_t stream)
{
    const float* x  = (const float*)d_in[0];   // [4096,1024] fp32
    const float* Wq = (const float*)d_in[1];
    const float* Wk = (const float*)d_in[2];
    const float* Wv = (const float*)d_in[3];
    const float* Wo = (const float*)d_in[4];
    const float* bo = (const float*)d_in[5];
    float* out = (float*)d_out;

    // ws (32 MB): xb -> ctx after gemm_qkv. d_out doubles as wqkvT scratch
    // until gemm2f overwrites it (wqkvT dead after gemm8p).
    unsigned short* xb     = (unsigned short*)d_ws;           // 8 MB -> ctx
    unsigned short* qb     = xb + (size_t)4096 * 1024;        // 8 MB
    unsigned short* kb     = qb + (size_t)4096 * 1024;        // 8 MB
    unsigned short* vT     = kb + (size_t)4096 * 1024;        // 8 MB [1024][4096]
    unsigned short* ctx    = xb;
    unsigned short* wqkvT  = (unsigned short*)d_out;          // 6.3 MB scratch

    prep<<<2816, 256, 0, stream>>>(x, xb, Wq, Wk, Wv, wqkvT);

    gemm8p<<<dim3(16, 32), 512, 0, stream>>>(xb, wqkvT, qb, kb, vT);

    attn11<<<dim3(16, 32), 256, 0, stream>>>(qb, kb, vT, ctx);

    gemm2f<<<dim3(8, 32), 256, 0, stream>>>(ctx, Wo, out, bo);
}

// Round 10
// 175.793 us; speedup vs baseline: 1.0656x; 1.0656x over previous
//
#include <hip/hip_runtime.h>

typedef __bf16 bf16x8 __attribute__((ext_vector_type(8)));
typedef float f32x4 __attribute__((ext_vector_type(4)));
typedef float f32x16 __attribute__((ext_vector_type(16)));
typedef unsigned int u32x4 __attribute__((ext_vector_type(4)));

__device__ inline unsigned short f2bf(float f) {
    unsigned int x = __builtin_bit_cast(unsigned int, f);
    x += 0x7fff + ((x >> 16) & 1);   // RNE; inputs finite
    return (unsigned short)(x >> 16);
}

// async global->LDS, 16B per lane; LDS dest = wave-uniform base + lane*16
__device__ __forceinline__ void gl_lds16(const unsigned short* g, unsigned short* l)
{
    __builtin_amdgcn_global_load_lds(
        (const __attribute__((address_space(1))) void*)g,
        (__attribute__((address_space(3))) void*)l, 16, 0, 0);
}

// ---------------------------------------------------------------------------
// Fused prep: blocks [0,2048): x fp32 -> xb bf16 (8 elems/thread).
// Blocks [2048,2816): Wq/Wk/Wv fp32 [k][n] -> wqkvT bf16 [n][k] (64x64 tiles).
// ---------------------------------------------------------------------------
__global__ __launch_bounds__(256)
void prep(const float* __restrict__ x, unsigned short* __restrict__ xb,
          const float* __restrict__ Wq, const float* __restrict__ Wk,
          const float* __restrict__ Wv, unsigned short* __restrict__ wT)
{
    __shared__ unsigned short T[64][72];
    if (blockIdx.x < 2048) {
        const size_t i = ((size_t)blockIdx.x * 256 + threadIdx.x) * 8;
        float4 a = *reinterpret_cast<const float4*>(x + i);
        float4 b = *reinterpret_cast<const float4*>(x + i + 4);
        unsigned short t[8] = { f2bf(a.x), f2bf(a.y), f2bf(a.z), f2bf(a.w),
                                f2bf(b.x), f2bf(b.y), f2bf(b.z), f2bf(b.w) };
        *reinterpret_cast<uint4*>(xb + i) = *reinterpret_cast<uint4*>(t);
        return;
    }
    const int blk = blockIdx.x - 2048;
    const int z = blk >> 8, within = blk & 255;
    const float* W = (z == 0) ? Wq : (z == 1) ? Wk : Wv;
    unsigned short* dstBase = wT + (size_t)z * 1024 * 1024;
    const int k0 = (within >> 4) * 64, n0 = (within & 15) * 64;
    const int r = threadIdx.x >> 2, c0 = (threadIdx.x & 3) * 16;
    const float* src = W + (size_t)(k0 + r) * 1024 + n0 + c0;
    #pragma unroll
    for (int j = 0; j < 16; j += 4) {
        float4 f = *reinterpret_cast<const float4*>(src + j);
        T[r][c0 + j]     = f2bf(f.x);
        T[r][c0 + j + 1] = f2bf(f.y);
        T[r][c0 + j + 2] = f2bf(f.z);
        T[r][c0 + j + 3] = f2bf(f.w);
    }
    __syncthreads();
    unsigned short* dst = dstBase + (size_t)(n0 + r) * 1024 + k0 + c0;
    #pragma unroll
    for (int h = 0; h < 2; ++h) {
        unsigned short t8[8];
        #pragma unroll
        for (int j = 0; j < 8; ++j) t8[j] = T[c0 + h * 8 + j][r];
        *reinterpret_cast<uint4*>(dst + h * 8) = *reinterpret_cast<uint4*>(t8);
    }
}

// ---------------------------------------------------------------------------
// Transpose-convert (Wo): fp32 [k][n] -> bf16 [n][k].
// ---------------------------------------------------------------------------
__global__ __launch_bounds__(256)
void wconv(const float* __restrict__ W, unsigned short* __restrict__ wT)
{
    __shared__ unsigned short T[64][72];
    const int k0 = blockIdx.y * 64, n0 = blockIdx.x * 64;
    const int r = threadIdx.x >> 2, c0 = (threadIdx.x & 3) * 16;
    const float* src = W + (size_t)(k0 + r) * 1024 + n0 + c0;
    #pragma unroll
    for (int j = 0; j < 16; j += 4) {
        float4 f = *reinterpret_cast<const float4*>(src + j);
        T[r][c0 + j]     = f2bf(f.x);
        T[r][c0 + j + 1] = f2bf(f.y);
        T[r][c0 + j + 2] = f2bf(f.z);
        T[r][c0 + j + 3] = f2bf(f.w);
    }
    __syncthreads();
    unsigned short* dst = wT + (size_t)(n0 + r) * 1024 + k0 + c0;
    #pragma unroll
    for (int h = 0; h < 2; ++h) {
        unsigned short t8[8];
        #pragma unroll
        for (int j = 0; j < 8; ++j) t8[j] = T[c0 + h * 8 + j][r];
        *reinterpret_cast<uint4*>(dst + h * 8) = *reinterpret_cast<uint4*>(t8);
    }
}

// ---------------------------------------------------------------------------
// gemm8p (R8-verified): QKV projection, 2-phase pipeline. BM=128 BN=192
// BK=64, grid 32x16 = 512 blocks = 2/CU, 8 waves (2Mx4N), acc[4][3].
// Per K-tile: issue 5 gl_lds for t+1 -> compute t -> vmcnt(0) + s_barrier.
// XOR-swizzled LDS reads via pre-swizzled gl_lds source.
// ---------------------------------------------------------------------------
__global__ __launch_bounds__(512, 4)
void gemm8p(const unsigned short* __restrict__ A,
            const unsigned short* __restrict__ BT,
            unsigned short* __restrict__ qb,
            unsigned short* __restrict__ kb,
            unsigned short* __restrict__ vT)
{
    __shared__ unsigned short As[2][128 * 64];   // 2 x 16 KB
    __shared__ unsigned short Bs[2][192 * 64];   // 2 x 24 KB

    const int tid  = threadIdx.x;
    const int wave = tid >> 6, lane = tid & 63;
    const int quad = lane >> 4, l16 = lane & 15;
    const int wm = wave >> 2, wn = wave & 3;     // 2 x 4 wave grid
    const int mBase = blockIdx.y * 128, nBase = blockIdx.x * 192;

    f32x4 acc[4][3] = {};

    const int arow = tid >> 3;                   // row-within-64
    const int u8   = (tid & 7) ^ (arow & 7);     // logical 16B unit 0..7
    const int rx   = l16 & 7;                    // read-side row&7

    auto stage = [&](int kb0, int buf) {         // exactly 5 gl_lds per thread
        #pragma unroll
        for (int i = 0; i < 2; ++i)
            gl_lds16(A + (size_t)(mBase + i * 64 + arow) * 1024 + kb0 + u8 * 8,
                     &As[buf][(i * 512 + wave * 64) * 8]);
        #pragma unroll
        for (int i = 0; i < 3; ++i)
            gl_lds16(BT + (size_t)(nBase + i * 64 + arow) * 1024 + kb0 + u8 * 8,
                     &Bs[buf][(i * 512 + wave * 64) * 8]);
    };

    stage(0, 0);
    __syncthreads();                             // tile 0 landed (full drain, once)

    for (int t = 0; t < 16; ++t) {
        const int buf = t & 1;
        if (t + 1 < 16)
            stage((t + 1) * 64, buf ^ 1);        // issue-early; drains at bottom

        #pragma unroll
        for (int kh = 0; kh < 2; ++kh) {
            bf16x8 af[4], bf[3];
            #pragma unroll
            for (int mr = 0; mr < 4; ++mr) {
                const int row = wm * 64 + mr * 16 + l16;
                af[mr] = *reinterpret_cast<const bf16x8*>(
                    &As[buf][row * 64 + (((kh * 4 + quad) ^ rx) * 8)]);
            }
            #pragma unroll
            for (int nr = 0; nr < 3; ++nr) {
                const int row = wn * 48 + nr * 16 + l16;
                bf[nr] = *reinterpret_cast<const bf16x8*>(
                    &Bs[buf][row * 64 + (((kh * 4 + quad) ^ rx) * 8)]);
            }
            #pragma unroll
            for (int mr = 0; mr < 4; ++mr)
                #pragma unroll
                for (int nr = 0; nr < 3; ++nr)
                    acc[mr][nr] = __builtin_amdgcn_mfma_f32_16x16x32_bf16(
                        af[mr], bf[nr], acc[mr][nr], 0, 0, 0);
        }

        if (t + 1 < 16) {
            asm volatile("s_waitcnt vmcnt(0)" ::: "memory");  // t+1 landed (had
            __builtin_amdgcn_s_barrier();                     // full compute to fly)
        }
    }

    // ---- epilogue: q/k normal, v transposed (boundaries are frag-aligned)
    #pragma unroll
    for (int mr = 0; mr < 4; ++mr) {
        const int row0 = mBase + wm * 64 + mr * 16 + quad * 4;
        #pragma unroll
        for (int nr = 0; nr < 3; ++nr) {
            const int col = nBase + wn * 48 + nr * 16 + l16;
            if (col < 1024) {
                #pragma unroll
                for (int i = 0; i < 4; ++i)
                    qb[(size_t)(row0 + i) * 1024 + col] = f2bf(acc[mr][nr][i]);
            } else if (col < 2048) {
                #pragma unroll
                for (int i = 0; i < 4; ++i)
                    kb[(size_t)(row0 + i) * 1024 + col - 1024] = f2bf(acc[mr][nr][i]);
            } else {
                unsigned short t4[4] = { f2bf(acc[mr][nr][0]), f2bf(acc[mr][nr][1]),
                                         f2bf(acc[mr][nr][2]), f2bf(acc[mr][nr][3]) };
                *reinterpret_cast<uint2*>(&vT[(size_t)(col - 2048) * 4096 + row0]) =
                    *reinterpret_cast<uint2*>(t4);
            }
        }
    }
}

// ---------------------------------------------------------------------------
// m97-style GEMM (R1-verified): out-projection, fp32 out + bias.
// ---------------------------------------------------------------------------
__global__ __launch_bounds__(256)
void gemm128o(const unsigned short* __restrict__ A,
              const unsigned short* __restrict__ BT,
              float* __restrict__ out, const float* __restrict__ bias)
{
    __shared__ unsigned short As[128 * 32];
    __shared__ unsigned short Bs[128 * 32];

    const int tid = threadIdx.x;
    const int wave = tid >> 6, lane = tid & 63, quad = lane >> 4, l16 = lane & 15;
    const int wm = wave >> 1, wn = wave & 1;
    const int mBase = blockIdx.y * 128, nBase = blockIdx.x * 128;

    f32x4 acc[4][4] = {};

    const int srow = lane >> 2, sko = (lane & 3) * 8;

    for (int kb = 0; kb < 1024; kb += 32) {
        __syncthreads();
        #pragma unroll
        for (int j = 0; j < 2; ++j) {
            const int seg = wave * 2 + j;
            gl_lds16(A  + (size_t)(mBase + seg * 16 + srow) * 1024 + kb + sko,
                     As + seg * 512);
            gl_lds16(BT + (size_t)(nBase + seg * 16 + srow) * 1024 + kb + sko,
                     Bs + seg * 512);
        }
        __syncthreads();

        bf16x8 af[4], bf[4];
        #pragma unroll
        for (int t = 0; t < 4; ++t) {
            af[t] = *reinterpret_cast<const bf16x8*>(&As[(wm * 64 + t * 16 + l16) * 32 + quad * 8]);
            bf[t] = *reinterpret_cast<const bf16x8*>(&Bs[(wn * 64 + t * 16 + l16) * 32 + quad * 8]);
        }
        #pragma unroll
        for (int ti = 0; ti < 4; ++ti)
            #pragma unroll
            for (int tj = 0; tj < 4; ++tj)
                acc[ti][tj] = __builtin_amdgcn_mfma_f32_16x16x32_bf16(
                    af[ti], bf[tj], acc[ti][tj], 0, 0, 0);
    }

    #pragma unroll
    for (int ti = 0; ti < 4; ++ti) {
        const int row0 = mBase + wm * 64 + ti * 16 + quad * 4;
        #pragma unroll
        for (int tj = 0; tj < 4; ++tj) {
            const int col = nBase + wn * 64 + tj * 16 + l16;
            const float ba = bias[col];
            #pragma unroll
            for (int i = 0; i < 4; ++i)
                out[(size_t)(row0 + i) * 1024 + col] = acc[ti][tj][i] + ba;
        }
    }
}

// ---------------------------------------------------------------------------
// attn12 = attn11 + ONE change: XCD-chunked block remap (T1). Grid (16,32)
// linearizes to L = j + 16*bh; hardware round-robins L&7 across XCDs, so
// the 16 blocks sharing one (b,h)'s K/V previously scattered across all 8
// XCD L2s (8x replication -> FETCH 62.5MB vs 24MB of q/k/v). Remap: XCD
// c = L&7 serves bh in [c*4, c*4+4) -> one (b,h)'s 0.5MB K/V lives in ONE
// L2; 4 groups = 2MB < 4MB per-XCD L2. Bijective (512 %% 8 == 0). Wrong
// dispatch-mapping assumption costs only speed, never correctness.
// Everything else identical to attn11 (R6-verified).
// ---------------------------------------------------------------------------
__global__ __launch_bounds__(256, 2)
void attn12(const unsigned short* __restrict__ q,
            const unsigned short* __restrict__ k,
            const unsigned short* __restrict__ vT,
            unsigned short* __restrict__ ctx)
{
    __shared__ unsigned short Ks[3][64 * 64];  // [buf][key][d], 16B units XOR-swizzled
    __shared__ unsigned short Vs[3][64 * 64];  // [buf][d][key], 16B units XOR-swizzled
    __shared__ float Lt[8 * 64];               // [wave*2+tile][lane] l partials

    const int tid  = threadIdx.x;
    const int wave = tid >> 6, lane = tid & 63;
    const int q32 = lane & 31, hi = lane >> 5;
    const int slice = wave & 1;                // 32-row q slice within 64-row macro tile
    const int ks    = wave >> 1;               // 32-key subtile within 64-key staged tile
    // XCD-chunked remap (T1): all 16 j-blocks of a (b,h) on one XCD.
    const int L   = (int)(blockIdx.x + (blockIdx.y << 4));
    const int xcd = L & 7, idx = L >> 3;       // idx 0..63
    const int bh  = xcd * 4 + (idx >> 4);
    const int j   = idx & 15;                  // 0..15 pair index
    const int b = bh >> 4, h = bh & 15;
    const int tokBase = b * 2048;
    const int colBase = h * 64;
    const int qtA = 31 - j, qtB = j;
    const int qloA = qtA * 64 + slice * 32;    // local (per-batch) q-row base of this wave
    const int qloB = qtB * 64 + slice * 32;

    // Q fragments (QK^T B-operand: lane col q = lane&31, d = c*16 + hi*8 + 0..7)
    bf16x8 aqA[4], aqB[4];
    {
        const unsigned short* ra = q + (size_t)(tokBase + qloA + q32) * 1024 + colBase + hi * 8;
        const unsigned short* rb = q + (size_t)(tokBase + qloB + q32) * 1024 + colBase + hi * 8;
        #pragma unroll
        for (int c = 0; c < 4; ++c) {
            aqA[c] = *reinterpret_cast<const bf16x8*>(ra + c * 16);
            aqB[c] = *reinterpret_cast<const bf16x8*>(rb + c * 16);
        }
    }
    // Pin Q here: its scoreboard wait lands pre-loop, so in-loop vmcnt
    // immediates count only staging loads.
    #pragma unroll
    for (int c = 0; c < 4; ++c)
        asm volatile("" :: "v"(aqA[c]), "v"(aqB[c]));

    f32x16 oA[2] = {}, oB[2] = {};             // [d-half], 32q x 32d each
    float lsA = 0.0f, lsB = 0.0f;

    // Staging: K tile = 64 key-rows x 64 d (128B rows, 8 x 16B units);
    // V tile = 64 d-rows x 64 keys. Linear LDS dest (slot s = r*8 + pu),
    // source pre-swizzled so content at unit pu is logical unit pu ^ (r&7).
    const int s0 = (wave * 2 + 0) * 64 + lane;
    const int s1 = (wave * 2 + 1) * 64 + lane;
    const int r0 = s0 >> 3, sw0 = (s0 & 7) ^ (r0 & 7);
    const int r1 = s1 >> 3, sw1 = (s1 & 7) ^ (r1 & 7);
    const size_t kOff0 = (size_t)r0 * 1024 + colBase + sw0 * 8;
    const size_t kOff1 = (size_t)r1 * 1024 + colBase + sw1 * 8;
    const size_t vOff0 = (size_t)(colBase + r0) * 4096 + sw0 * 8;
    const size_t vOff1 = (size_t)(colBase + r1) * 4096 + sw1 * 8;

    auto stage = [&](int tok0, int buf) {      // exactly 4 VMEM loads per wave
        gl_lds16(k  + (size_t)tok0 * 1024 + kOff0, &Ks[buf][(wave * 2 + 0) * 512]);
        gl_lds16(k  + (size_t)tok0 * 1024 + kOff1, &Ks[buf][(wave * 2 + 1) * 512]);
        gl_lds16(vT + vOff0 + tok0,                &Vs[buf][(wave * 2 + 0) * 512]);
        gl_lds16(vT + vOff1 + tok0,                &Vs[buf][(wave * 2 + 1) * 512]);
    };

    bf16x8 ak[4];       // K frags (shared by tiles A and B)
    bf16x8 bv[2][2];    // V frags [k-chunk][d-half] (shared by A and B)

    const int nkt = qtA + 1;                   // 64-key tiles; >= 17 always
    stage(tokBase, 0);                         // prologue: 2 tiles in flight
    stage(tokBase + 64, 1);

    int cur = 0;                               // buffer holding tile kt
    const int krowK = ks * 32 + q32;           // K-frag LDS row for this wave
    for (int kt = 0; kt < nkt; ++kt) {
        // retire tile kt's 4 loads; leave tile kt+1's 4 in flight
        if (kt + 1 < nkt) asm volatile("s_waitcnt vmcnt(4)" ::: "memory");
        else              asm volatile("s_waitcnt vmcnt(0)" ::: "memory");
        __builtin_amdgcn_s_barrier();
        asm volatile("" ::: "memory");

        const int stg = (cur == 0) ? 2 : cur - 1;        // (cur+2)%3
        if (kt + 2 < nkt)
            stage(tokBase + (kt + 2) * 64, stg);         // lands ~2 iters out

        const unsigned short* KsB = Ks[cur];
        const unsigned short* VsB = Vs[cur];
        #pragma unroll
        for (int c = 0; c < 4; ++c) {
            const int u = c * 2 + hi;
            ak[c] = *reinterpret_cast<const bf16x8*>(
                &KsB[krowK * 64 + ((u ^ (krowK & 7)) * 8)]);
        }
        #pragma unroll
        for (int kc = 0; kc < 2; ++kc)
            #pragma unroll
            for (int dh = 0; dh < 2; ++dh) {
                const int vrow = dh * 32 + q32;
                const int u = ks * 4 + kc * 2 + hi;
                bv[kc][dh] = *reinterpret_cast<const bf16x8*>(
                    &VsB[vrow * 64 + ((u ^ (vrow & 7)) * 8)]);
            }

        const int klo = kt * 64 + ks * 32;
        const bool dB = (klo <= qloB + 31);
        const bool dA = (klo <= qloA + 31);

        if (dB) {
            // ---- fused A+B (shared iter): one straight-line block ----
            f32x16 scA = (f32x16)0.0f, scB = (f32x16)0.0f;
            #pragma unroll
            for (int c = 0; c < 4; ++c) {
                scA = __builtin_amdgcn_mfma_f32_32x32x16_bf16(ak[c], aqA[c], scA, 0, 0, 0);
                scB = __builtin_amdgcn_mfma_f32_32x32x16_bf16(ak[c], aqB[c], scB, 0, 0, 0);
            }
            float pA[16], pB[16];
            #pragma unroll
            for (int r = 0; r < 16; ++r) {
                pA[r] = __expf(scA[r] * 0.125f);
                pB[r] = __expf(scB[r] * 0.125f);
            }
            if (klo + 31 > qloB) {                       // diagB only (diagA impossible)
                #pragma unroll
                for (int r = 0; r < 16; ++r) {
                    const int krow = (r & 3) + 8 * (r >> 2) + 4 * hi;
                    if (klo + krow > qloB + q32) pB[r] = 0.0f;
                }
            }
            #pragma unroll
            for (int r = 0; r < 16; ++r) { lsA += pA[r]; lsB += pB[r]; }
            unsigned int pkA[8], pkB[8];
            #pragma unroll
            for (int i = 0; i < 8; ++i) {
                asm("v_cvt_pk_bf16_f32 %0, %1, %2"
                    : "=v"(pkA[i]) : "v"(pA[2 * i]), "v"(pA[2 * i + 1]));
                asm("v_cvt_pk_bf16_f32 %0, %1, %2"
                    : "=v"(pkB[i]) : "v"(pB[2 * i]), "v"(pB[2 * i + 1]));
            }
            #pragma unroll
            for (int kc = 0; kc < 2; ++kc) {
                unsigned int xa0 = pkA[kc * 4 + 0], ya0 = pkA[kc * 4 + 2];
                unsigned int xa1 = pkA[kc * 4 + 1], ya1 = pkA[kc * 4 + 3];
                unsigned int xb0 = pkB[kc * 4 + 0], yb0 = pkB[kc * 4 + 2];
                unsigned int xb1 = pkB[kc * 4 + 1], yb1 = pkB[kc * 4 + 3];
                asm("v_permlane32_swap_b32 %0, %1" : "+v"(xa0), "+v"(ya0));
                asm("v_permlane32_swap_b32 %0, %1" : "+v"(xa1), "+v"(ya1));
                asm("v_permlane32_swap_b32 %0, %1" : "+v"(xb0), "+v"(yb0));
                asm("v_permlane32_swap_b32 %0, %1" : "+v"(xb1), "+v"(yb1));
                const u32x4 wa = { xa0, xa1, ya0, ya1 };
                const u32x4 wb = { xb0, xb1, yb0, yb1 };
                const bf16x8 paA = __builtin_bit_cast(bf16x8, wa);
                const bf16x8 paB = __builtin_bit_cast(bf16x8, wb);
                #pragma unroll
                for (int dh = 0; dh < 2; ++dh) {
                    oA[dh] = __builtin_amdgcn_mfma_f32_32x32x16_bf16(paA, bv[kc][dh], oA[dh], 0, 0, 0);
                    oB[dh] = __builtin_amdgcn_mfma_f32_32x32x16_bf16(paB, bv[kc][dh], oB[dh], 0, 0, 0);
                }
            }
        } else if (dA) {
            // ---- A only ----
            f32x16 sc = (f32x16)0.0f;
            #pragma unroll
            for (int c = 0; c < 4; ++c)
                sc = __builtin_amdgcn_mfma_f32_32x32x16_bf16(ak[c], aqA[c], sc, 0, 0, 0);
            float p[16];
            #pragma unroll
            for (int r = 0; r < 16; ++r) p[r] = __expf(sc[r] * 0.125f);
            if (klo + 31 > qloA) {                       // diagonal block: causal mask
                #pragma unroll
                for (int r = 0; r < 16; ++r) {
                    const int krow = (r & 3) + 8 * (r >> 2) + 4 * hi;
                    if (klo + krow > qloA + q32) p[r] = 0.0f;
                }
            }
            #pragma unroll
            for (int r = 0; r < 16; ++r) lsA += p[r];
            unsigned int pk[8];
            #pragma unroll
            for (int i = 0; i < 8; ++i)
                asm("v_cvt_pk_bf16_f32 %0, %1, %2"
                    : "=v"(pk[i]) : "v"(p[2 * i]), "v"(p[2 * i + 1]));
            #pragma unroll
            for (int kc = 0; kc < 2; ++kc) {
                unsigned int x0 = pk[kc * 4 + 0], y0 = pk[kc * 4 + 2];
                unsigned int x1 = pk[kc * 4 + 1], y1 = pk[kc * 4 + 3];
                asm("v_permlane32_swap_b32 %0, %1" : "+v"(x0), "+v"(y0));
                asm("v_permlane32_swap_b32 %0, %1" : "+v"(x1), "+v"(y1));
                const u32x4 wv = { x0, x1, y0, y1 };
                const bf16x8 pa = __builtin_bit_cast(bf16x8, wv);
                #pragma unroll
                for (int dh = 0; dh < 2; ++dh)
                    oA[dh] = __builtin_amdgcn_mfma_f32_32x32x16_bf16(pa, bv[kc][dh], oA[dh], 0, 0, 0);
            }
        }
        cur = (cur == 2) ? 0 : cur + 1;
    }

    // ---- epilogue: combine the two k-subtile partials per q-slice, normalize
    float* Obuf = reinterpret_cast<float*>(&Ks[0][0]);   // 2 slots x 8KB (overlay)

    __syncthreads();                           // all compute reads done; overlay safe
    Lt[(wave * 2 + 0) * 64 + lane] = lsA;
    Lt[(wave * 2 + 1) * 64 + lane] = lsB;

    auto writePartial = [&](const f32x16 (&o)[2]) {
        float* slot = Obuf + slice * 2048;
        #pragma unroll
        for (int r = 0; r < 16; ++r) {
            const int row = (r & 3) + 8 * (r >> 2) + 4 * hi;
            #pragma unroll
            for (int dh = 0; dh < 2; ++dh)
                slot[row * 64 + dh * 32 + q32] = o[dh][r];
        }
    };
    auto finalize = [&](int t, int qt, const f32x16 (&o)[2]) {
        const float lf = Lt[(slice * 2 + t) * 64 + q32]
                       + Lt[(slice * 2 + t) * 64 + 32 + q32]
                       + Lt[((slice + 2) * 2 + t) * 64 + q32]
                       + Lt[((slice + 2) * 2 + t) * 64 + 32 + q32];
        const float inv = 1.0f / lf;
        const float* slot = Obuf + slice * 2048;
        #pragma unroll
        for (int r = 0; r < 16; ++r) {
            const int row = (r & 3) + 8 * (r >> 2) + 4 * hi;
            const float invr = __shfl(inv, row);
            const size_t gr = (size_t)(tokBase + qt * 64 + slice * 32 + row) * 1024 + colBase;
            #pragma unroll
            for (int dh = 0; dh < 2; ++dh)
                ctx[gr + dh * 32 + q32] =
                    f2bf((o[dh][r] + slot[row * 64 + dh * 32 + q32]) * invr);
        }
    };

    if (ks == 1) writePartial(oA);             // waves 2,3 publish A partials
    __syncthreads();
    if (ks == 0) finalize(0, qtA, oA);         // waves 0,1 finalize tile A
    __syncthreads();
    if (ks == 0) writePartial(oB);             // waves 0,1 publish B partials
    __syncthreads();
    if (ks == 1) finalize(1, qtB, oB);         // waves 2,3 finalize tile B
}

// ---------------------------------------------------------------------------
extern "C" void kernel_launch(void* const* d_in, const int* in_sizes, int n_in,
                              void* d_out, int out_size, void* d_ws, size_t ws_size,
                              hipStream_t stream)
{
    const float* x  = (const float*)d_in[0];   // [4096,1024] fp32
    const float* Wq = (const float*)d_in[1];
    const float* Wk = (const float*)d_in[2];
    const float* Wv = (const float*)d_in[3];
    const float* Wo = (const float*)d_in[4];
    const float* bo = (const float*)d_in[5];
    float* out = (float*)d_out;

    // ws (32 MB): xb -> ctx after gemm_qkv; kb -> woT after attn.
    // d_out doubles as wqkvT scratch until gemm128o overwrites it.
    unsigned short* xb     = (unsigned short*)d_ws;           // 8 MB -> ctx
    unsigned short* qb     = xb + (size_t)4096 * 1024;        // 8 MB
    unsigned short* kb     = qb + (size_t)4096 * 1024;        // 8 MB -> woT
    unsigned short* vT     = kb + (size_t)4096 * 1024;        // 8 MB [1024][4096]
    unsigned short* ctx    = xb;
    unsigned short* wqkvT  = (unsigned short*)d_out;          // 6.3 MB scratch
    unsigned short* woT    = kb;

    prep<<<2816, 256, 0, stream>>>(x, xb, Wq, Wk, Wv, wqkvT);

    gemm8p<<<dim3(16, 32), 512, 0, stream>>>(xb, wqkvT, qb, kb, vT);

    attn12<<<dim3(16, 32), 256, 0, stream>>>(qb, kb, vT, ctx);

    wconv<<<dim3(16, 16), 256, 0, stream>>>(Wo, woT);

    gemm128o<<<dim3(8, 32), 256, 0, stream>>>(ctx, woT, out, bo);
}

// Round 11
// 175.145 us; speedup vs baseline: 1.0695x; 1.0037x over previous
//
#include <hip/hip_runtime.h>

typedef __bf16 bf16x8 __attribute__((ext_vector_type(8)));
typedef float f32x4 __attribute__((ext_vector_type(4)));
typedef float f32x16 __attribute__((ext_vector_type(16)));
typedef unsigned int u32x4 __attribute__((ext_vector_type(4)));

__device__ inline unsigned short f2bf(float f) {
    unsigned int x = __builtin_bit_cast(unsigned int, f);
    x += 0x7fff + ((x >> 16) & 1);   // RNE; inputs finite
    return (unsigned short)(x >> 16);
}

// async global->LDS, 16B per lane; LDS dest = wave-uniform base + lane*16
__device__ __forceinline__ void gl_lds16(const unsigned short* g, unsigned short* l)
{
    __builtin_amdgcn_global_load_lds(
        (const __attribute__((address_space(1))) void*)g,
        (__attribute__((address_space(3))) void*)l, 16, 0, 0);
}

// ---------------------------------------------------------------------------
// Fused prep: blocks [0,2048): x fp32 -> xb bf16 (8 elems/thread).
// Blocks [2048,2816): Wq/Wk/Wv fp32 [k][n] -> wqkvT bf16 [n][k] (64x64 tiles).
// ---------------------------------------------------------------------------
__global__ __launch_bounds__(256)
void prep(const float* __restrict__ x, unsigned short* __restrict__ xb,
          const float* __restrict__ Wq, const float* __restrict__ Wk,
          const float* __restrict__ Wv, unsigned short* __restrict__ wT)
{
    __shared__ unsigned short T[64][72];
    if (blockIdx.x < 2048) {
        const size_t i = ((size_t)blockIdx.x * 256 + threadIdx.x) * 8;
        float4 a = *reinterpret_cast<const float4*>(x + i);
        float4 b = *reinterpret_cast<const float4*>(x + i + 4);
        unsigned short t[8] = { f2bf(a.x), f2bf(a.y), f2bf(a.z), f2bf(a.w),
                                f2bf(b.x), f2bf(b.y), f2bf(b.z), f2bf(b.w) };
        *reinterpret_cast<uint4*>(xb + i) = *reinterpret_cast<uint4*>(t);
        return;
    }
    const int blk = blockIdx.x - 2048;
    const int z = blk >> 8, within = blk & 255;
    const float* W = (z == 0) ? Wq : (z == 1) ? Wk : Wv;
    unsigned short* dstBase = wT + (size_t)z * 1024 * 1024;
    const int k0 = (within >> 4) * 64, n0 = (within & 15) * 64;
    const int r = threadIdx.x >> 2, c0 = (threadIdx.x & 3) * 16;
    const float* src = W + (size_t)(k0 + r) * 1024 + n0 + c0;
    #pragma unroll
    for (int j = 0; j < 16; j += 4) {
        float4 f = *reinterpret_cast<const float4*>(src + j);
        T[r][c0 + j]     = f2bf(f.x);
        T[r][c0 + j + 1] = f2bf(f.y);
        T[r][c0 + j + 2] = f2bf(f.z);
        T[r][c0 + j + 3] = f2bf(f.w);
    }
    __syncthreads();
    unsigned short* dst = dstBase + (size_t)(n0 + r) * 1024 + k0 + c0;
    #pragma unroll
    for (int h = 0; h < 2; ++h) {
        unsigned short t8[8];
        #pragma unroll
        for (int j = 0; j < 8; ++j) t8[j] = T[c0 + h * 8 + j][r];
        *reinterpret_cast<uint4*>(dst + h * 8) = *reinterpret_cast<uint4*>(t8);
    }
}

// ---------------------------------------------------------------------------
// Transpose-convert (Wo): fp32 [k][n] -> bf16 [n][k].
// ---------------------------------------------------------------------------
__global__ __launch_bounds__(256)
void wconv(const float* __restrict__ W, unsigned short* __restrict__ wT)
{
    __shared__ unsigned short T[64][72];
    const int k0 = blockIdx.y * 64, n0 = blockIdx.x * 64;
    const int r = threadIdx.x >> 2, c0 = (threadIdx.x & 3) * 16;
    const float* src = W + (size_t)(k0 + r) * 1024 + n0 + c0;
    #pragma unroll
    for (int j = 0; j < 16; j += 4) {
        float4 f = *reinterpret_cast<const float4*>(src + j);
        T[r][c0 + j]     = f2bf(f.x);
        T[r][c0 + j + 1] = f2bf(f.y);
        T[r][c0 + j + 2] = f2bf(f.z);
        T[r][c0 + j + 3] = f2bf(f.w);
    }
    __syncthreads();
    unsigned short* dst = wT + (size_t)(n0 + r) * 1024 + k0 + c0;
    #pragma unroll
    for (int h = 0; h < 2; ++h) {
        unsigned short t8[8];
        #pragma unroll
        for (int j = 0; j < 8; ++j) t8[j] = T[c0 + h * 8 + j][r];
        *reinterpret_cast<uint4*>(dst + h * 8) = *reinterpret_cast<uint4*>(t8);
    }
}

// ---------------------------------------------------------------------------
// gemm8p (R8-verified): QKV projection, 2-phase pipeline. BM=128 BN=192
// BK=64, grid 32x16 = 512 blocks = 2/CU, 8 waves (2Mx4N), acc[4][3].
// Per K-tile: issue 5 gl_lds for t+1 -> compute t -> vmcnt(0) + s_barrier.
// XOR-swizzled LDS reads via pre-swizzled gl_lds source.
// ---------------------------------------------------------------------------
__global__ __launch_bounds__(512, 4)
void gemm8p(const unsigned short* __restrict__ A,
            const unsigned short* __restrict__ BT,
            unsigned short* __restrict__ qb,
            unsigned short* __restrict__ kb,
            unsigned short* __restrict__ vT)
{
    __shared__ unsigned short As[2][128 * 64];   // 2 x 16 KB
    __shared__ unsigned short Bs[2][192 * 64];   // 2 x 24 KB

    const int tid  = threadIdx.x;
    const int wave = tid >> 6, lane = tid & 63;
    const int quad = lane >> 4, l16 = lane & 15;
    const int wm = wave >> 2, wn = wave & 3;     // 2 x 4 wave grid
    const int mBase = blockIdx.y * 128, nBase = blockIdx.x * 192;

    f32x4 acc[4][3] = {};

    const int arow = tid >> 3;                   // row-within-64
    const int u8   = (tid & 7) ^ (arow & 7);     // logical 16B unit 0..7
    const int rx   = l16 & 7;                    // read-side row&7

    auto stage = [&](int kb0, int buf) {         // exactly 5 gl_lds per thread
        #pragma unroll
        for (int i = 0; i < 2; ++i)
            gl_lds16(A + (size_t)(mBase + i * 64 + arow) * 1024 + kb0 + u8 * 8,
                     &As[buf][(i * 512 + wave * 64) * 8]);
        #pragma unroll
        for (int i = 0; i < 3; ++i)
            gl_lds16(BT + (size_t)(nBase + i * 64 + arow) * 1024 + kb0 + u8 * 8,
                     &Bs[buf][(i * 512 + wave * 64) * 8]);
    };

    stage(0, 0);
    __syncthreads();                             // tile 0 landed (full drain, once)

    for (int t = 0; t < 16; ++t) {
        const int buf = t & 1;
        if (t + 1 < 16)
            stage((t + 1) * 64, buf ^ 1);        // issue-early; drains at bottom

        #pragma unroll
        for (int kh = 0; kh < 2; ++kh) {
            bf16x8 af[4], bf[3];
            #pragma unroll
            for (int mr = 0; mr < 4; ++mr) {
                const int row = wm * 64 + mr * 16 + l16;
                af[mr] = *reinterpret_cast<const bf16x8*>(
                    &As[buf][row * 64 + (((kh * 4 + quad) ^ rx) * 8)]);
            }
            #pragma unroll
            for (int nr = 0; nr < 3; ++nr) {
                const int row = wn * 48 + nr * 16 + l16;
                bf[nr] = *reinterpret_cast<const bf16x8*>(
                    &Bs[buf][row * 64 + (((kh * 4 + quad) ^ rx) * 8)]);
            }
            #pragma unroll
            for (int mr = 0; mr < 4; ++mr)
                #pragma unroll
                for (int nr = 0; nr < 3; ++nr)
                    acc[mr][nr] = __builtin_amdgcn_mfma_f32_16x16x32_bf16(
                        af[mr], bf[nr], acc[mr][nr], 0, 0, 0);
        }

        if (t + 1 < 16) {
            asm volatile("s_waitcnt vmcnt(0)" ::: "memory");  // t+1 landed (had
            __builtin_amdgcn_s_barrier();                     // full compute to fly)
        }
    }

    // ---- epilogue: q/k normal, v transposed (boundaries are frag-aligned)
    #pragma unroll
    for (int mr = 0; mr < 4; ++mr) {
        const int row0 = mBase + wm * 64 + mr * 16 + quad * 4;
        #pragma unroll
        for (int nr = 0; nr < 3; ++nr) {
            const int col = nBase + wn * 48 + nr * 16 + l16;
            if (col < 1024) {
                #pragma unroll
                for (int i = 0; i < 4; ++i)
                    qb[(size_t)(row0 + i) * 1024 + col] = f2bf(acc[mr][nr][i]);
            } else if (col < 2048) {
                #pragma unroll
                for (int i = 0; i < 4; ++i)
                    kb[(size_t)(row0 + i) * 1024 + col - 1024] = f2bf(acc[mr][nr][i]);
            } else {
                unsigned short t4[4] = { f2bf(acc[mr][nr][0]), f2bf(acc[mr][nr][1]),
                                         f2bf(acc[mr][nr][2]), f2bf(acc[mr][nr][3]) };
                *reinterpret_cast<uint2*>(&vT[(size_t)(col - 2048) * 4096 + row0]) =
                    *reinterpret_cast<uint2*>(t4);
            }
        }
    }
}

// ---------------------------------------------------------------------------
// gemm_op: out-projection out = ctx @ woT^T + bias, 2-phase pipeline (port
// of the R8-verified gemm8p structure). BM=128 BN=64 BK=64 -> grid (16,32)
// = 512 blocks = 2/CU (not 128x128: that gives 256 blocks = 1/CU, the R3
// trap). 256 threads = 4 waves (2Mx2N), wave tile 64x32, acc[4][2]; per
// K-tile 12 swizzled ds_read_b128 + 16 MFMA. LDS 48KB double-buffered.
// Per iteration: issue 6 uniform gl_lds for t+1 -> compute t -> vmcnt(0) +
// raw s_barrier (staging DMA overlaps the whole compute phase).
// Same 8-unit XOR swizzle as gemm8p: linear LDS dest, inverse-swizzled
// global source; read rows are == l16 (mod 8) for both A and B tiles.
// WAR safety: identical to gemm8p (buf^1 reads finished one barrier ago;
// tile t's loads drained by the previous bottom vmcnt(0)).
// ---------------------------------------------------------------------------
__global__ __launch_bounds__(256, 2)
void gemm_op(const unsigned short* __restrict__ A,    // ctx bf16 [4096][1024]
             const unsigned short* __restrict__ BT,   // woT bf16 [1024][1024]
             float* __restrict__ out, const float* __restrict__ bias)
{
    __shared__ unsigned short As[2][128 * 64];   // 2 x 16 KB
    __shared__ unsigned short Bs[2][64 * 64];    // 2 x 8 KB

    const int tid  = threadIdx.x;
    const int wave = tid >> 6, lane = tid & 63;
    const int quad = lane >> 4, l16 = lane & 15;
    const int wm = wave >> 1, wn = wave & 1;     // 2 x 2 wave grid
    const int mBase = blockIdx.y * 128, nBase = blockIdx.x * 64;

    f32x4 acc[4][2] = {};

    // Staging geometry: slot s = i*256 + tid -> LDS row r = i*32 + (tid>>3),
    // physical unit pu = tid&7; source fetches logical unit u = pu ^ (r&7)
    // (i*32 vanishes mod 8).
    const int arow = tid >> 3;                   // 0..31
    const int u8   = (tid & 7) ^ (arow & 7);     // logical 16B unit 0..7
    const int rx   = l16 & 7;                    // read-side row&7

    auto stage = [&](int kb0, int buf) {         // exactly 6 gl_lds per thread
        #pragma unroll
        for (int i = 0; i < 4; ++i)
            gl_lds16(A + (size_t)(mBase + i * 32 + arow) * 1024 + kb0 + u8 * 8,
                     &As[buf][(i * 256 + tid) * 8]);
        #pragma unroll
        for (int i = 0; i < 2; ++i)
            gl_lds16(BT + (size_t)(nBase + i * 32 + arow) * 1024 + kb0 + u8 * 8,
                     &Bs[buf][(i * 256 + tid) * 8]);
    };

    stage(0, 0);
    __syncthreads();                             // tile 0 landed (full drain, once)

    for (int t = 0; t < 16; ++t) {
        const int buf = t & 1;
        if (t + 1 < 16)
            stage((t + 1) * 64, buf ^ 1);        // issue-early; drains at bottom

        #pragma unroll
        for (int kh = 0; kh < 2; ++kh) {
            bf16x8 af[4], bf[2];
            #pragma unroll
            for (int mr = 0; mr < 4; ++mr) {
                const int row = wm * 64 + mr * 16 + l16;
                af[mr] = *reinterpret_cast<const bf16x8*>(
                    &As[buf][row * 64 + (((kh * 4 + quad) ^ rx) * 8)]);
            }
            #pragma unroll
            for (int nr = 0; nr < 2; ++nr) {
                const int row = wn * 32 + nr * 16 + l16;
                bf[nr] = *reinterpret_cast<const bf16x8*>(
                    &Bs[buf][row * 64 + (((kh * 4 + quad) ^ rx) * 8)]);
            }
            #pragma unroll
            for (int mr = 0; mr < 4; ++mr)
                #pragma unroll
                for (int nr = 0; nr < 2; ++nr)
                    acc[mr][nr] = __builtin_amdgcn_mfma_f32_16x16x32_bf16(
                        af[mr], bf[nr], acc[mr][nr], 0, 0, 0);
        }

        if (t + 1 < 16) {
            asm volatile("s_waitcnt vmcnt(0)" ::: "memory");  // t+1 landed (had
            __builtin_amdgcn_s_barrier();                     // full compute to fly)
        }
    }

    // ---- epilogue: fp32 out + bias
    #pragma unroll
    for (int mr = 0; mr < 4; ++mr) {
        const int row0 = mBase + wm * 64 + mr * 16 + quad * 4;
        #pragma unroll
        for (int nr = 0; nr < 2; ++nr) {
            const int col = nBase + wn * 32 + nr * 16 + l16;
            const float ba = bias[col];
            #pragma unroll
            for (int i = 0; i < 4; ++i)
                out[(size_t)(row0 + i) * 1024 + col] = acc[mr][nr][i] + ba;
        }
    }
}

// ---------------------------------------------------------------------------
// attn12 (R10-verified): swapped-QK^T 32x32x16 flash attention with fused
// A/B shared iterations, in-register softmax (cvt_pk + permlane),
// XOR-swizzled K/V staging, 3-buffer counted-vmcnt staging, triangle fold,
// XCD-chunked block remap (one (b,h)'s 16 blocks on one XCD -> K/V
// L2-resident), LDS partial-combine epilogue.
// ---------------------------------------------------------------------------
__global__ __launch_bounds__(256, 2)
void attn12(const unsigned short* __restrict__ q,
            const unsigned short* __restrict__ k,
            const unsigned short* __restrict__ vT,
            unsigned short* __restrict__ ctx)
{
    __shared__ unsigned short Ks[3][64 * 64];  // [buf][key][d], 16B units XOR-swizzled
    __shared__ unsigned short Vs[3][64 * 64];  // [buf][d][key], 16B units XOR-swizzled
    __shared__ float Lt[8 * 64];               // [wave*2+tile][lane] l partials

    const int tid  = threadIdx.x;
    const int wave = tid >> 6, lane = tid & 63;
    const int q32 = lane & 31, hi = lane >> 5;
    const int slice = wave & 1;                // 32-row q slice within 64-row macro tile
    const int ks    = wave >> 1;               // 32-key subtile within 64-key staged tile
    // XCD-chunked remap (T1): all 16 j-blocks of a (b,h) on one XCD.
    const int L   = (int)(blockIdx.x + (blockIdx.y << 4));
    const int xcd = L & 7, idx = L >> 3;       // idx 0..63
    const int bh  = xcd * 4 + (idx >> 4);
    const int j   = idx & 15;                  // 0..15 pair index
    const int b = bh >> 4, h = bh & 15;
    const int tokBase = b * 2048;
    const int colBase = h * 64;
    const int qtA = 31 - j, qtB = j;
    const int qloA = qtA * 64 + slice * 32;    // local (per-batch) q-row base of this wave
    const int qloB = qtB * 64 + slice * 32;

    // Q fragments (QK^T B-operand: lane col q = lane&31, d = c*16 + hi*8 + 0..7)
    bf16x8 aqA[4], aqB[4];
    {
        const unsigned short* ra = q + (size_t)(tokBase + qloA + q32) * 1024 + colBase + hi * 8;
        const unsigned short* rb = q + (size_t)(tokBase + qloB + q32) * 1024 + colBase + hi * 8;
        #pragma unroll
        for (int c = 0; c < 4; ++c) {
            aqA[c] = *reinterpret_cast<const bf16x8*>(ra + c * 16);
            aqB[c] = *reinterpret_cast<const bf16x8*>(rb + c * 16);
        }
    }
    // Pin Q here: its scoreboard wait lands pre-loop, so in-loop vmcnt
    // immediates count only staging loads.
    #pragma unroll
    for (int c = 0; c < 4; ++c)
        asm volatile("" :: "v"(aqA[c]), "v"(aqB[c]));

    f32x16 oA[2] = {}, oB[2] = {};             // [d-half], 32q x 32d each
    float lsA = 0.0f, lsB = 0.0f;

    // Staging: K tile = 64 key-rows x 64 d (128B rows, 8 x 16B units);
    // V tile = 64 d-rows x 64 keys. Linear LDS dest (slot s = r*8 + pu),
    // source pre-swizzled so content at unit pu is logical unit pu ^ (r&7).
    const int s0 = (wave * 2 + 0) * 64 + lane;
    const int s1 = (wave * 2 + 1) * 64 + lane;
    const int r0 = s0 >> 3, sw0 = (s0 & 7) ^ (r0 & 7);
    const int r1 = s1 >> 3, sw1 = (s1 & 7) ^ (r1 & 7);
    const size_t kOff0 = (size_t)r0 * 1024 + colBase + sw0 * 8;
    const size_t kOff1 = (size_t)r1 * 1024 + colBase + sw1 * 8;
    const size_t vOff0 = (size_t)(colBase + r0) * 4096 + sw0 * 8;
    const size_t vOff1 = (size_t)(colBase + r1) * 4096 + sw1 * 8;

    auto stage = [&](int tok0, int buf) {      // exactly 4 VMEM loads per wave
        gl_lds16(k  + (size_t)tok0 * 1024 + kOff0, &Ks[buf][(wave * 2 + 0) * 512]);
        gl_lds16(k  + (size_t)tok0 * 1024 + kOff1, &Ks[buf][(wave * 2 + 1) * 512]);
        gl_lds16(vT + vOff0 + tok0,                &Vs[buf][(wave * 2 + 0) * 512]);
        gl_lds16(vT + vOff1 + tok0,                &Vs[buf][(wave * 2 + 1) * 512]);
    };

    bf16x8 ak[4];       // K frags (shared by tiles A and B)
    bf16x8 bv[2][2];    // V frags [k-chunk][d-half] (shared by A and B)

    const int nkt = qtA + 1;                   // 64-key tiles; >= 17 always
    stage(tokBase, 0);                         // prologue: 2 tiles in flight
    stage(tokBase + 64, 1);

    int cur = 0;                               // buffer holding tile kt
    const int krowK = ks * 32 + q32;           // K-frag LDS row for this wave
    for (int kt = 0; kt < nkt; ++kt) {
        // retire tile kt's 4 loads; leave tile kt+1's 4 in flight
        if (kt + 1 < nkt) asm volatile("s_waitcnt vmcnt(4)" ::: "memory");
        else              asm volatile("s_waitcnt vmcnt(0)" ::: "memory");
        __builtin_amdgcn_s_barrier();
        asm volatile("" ::: "memory");

        const int stg = (cur == 0) ? 2 : cur - 1;        // (cur+2)%3
        if (kt + 2 < nkt)
            stage(tokBase + (kt + 2) * 64, stg);         // lands ~2 iters out

        const unsigned short* KsB = Ks[cur];
        const unsigned short* VsB = Vs[cur];
        #pragma unroll
        for (int c = 0; c < 4; ++c) {
            const int u = c * 2 + hi;
            ak[c] = *reinterpret_cast<const bf16x8*>(
                &KsB[krowK * 64 + ((u ^ (krowK & 7)) * 8)]);
        }
        #pragma unroll
        for (int kc = 0; kc < 2; ++kc)
            #pragma unroll
            for (int dh = 0; dh < 2; ++dh) {
                const int vrow = dh * 32 + q32;
                const int u = ks * 4 + kc * 2 + hi;
                bv[kc][dh] = *reinterpret_cast<const bf16x8*>(
                    &VsB[vrow * 64 + ((u ^ (vrow & 7)) * 8)]);
            }

        const int klo = kt * 64 + ks * 32;
        const bool dB = (klo <= qloB + 31);
        const bool dA = (klo <= qloA + 31);

        if (dB) {
            // ---- fused A+B (shared iter): one straight-line block ----
            f32x16 scA = (f32x16)0.0f, scB = (f32x16)0.0f;
            #pragma unroll
            for (int c = 0; c < 4; ++c) {
                scA = __builtin_amdgcn_mfma_f32_32x32x16_bf16(ak[c], aqA[c], scA, 0, 0, 0);
                scB = __builtin_amdgcn_mfma_f32_32x32x16_bf16(ak[c], aqB[c], scB, 0, 0, 0);
            }
            float pA[16], pB[16];
            #pragma unroll
            for (int r = 0; r < 16; ++r) {
                pA[r] = __expf(scA[r] * 0.125f);
                pB[r] = __expf(scB[r] * 0.125f);
            }
            if (klo + 31 > qloB) {                       // diagB only (diagA impossible)
                #pragma unroll
                for (int r = 0; r < 16; ++r) {
                    const int krow = (r & 3) + 8 * (r >> 2) + 4 * hi;
                    if (klo + krow > qloB + q32) pB[r] = 0.0f;
                }
            }
            #pragma unroll
            for (int r = 0; r < 16; ++r) { lsA += pA[r]; lsB += pB[r]; }
            unsigned int pkA[8], pkB[8];
            #pragma unroll
            for (int i = 0; i < 8; ++i) {
                asm("v_cvt_pk_bf16_f32 %0, %1, %2"
                    : "=v"(pkA[i]) : "v"(pA[2 * i]), "v"(pA[2 * i + 1]));
                asm("v_cvt_pk_bf16_f32 %0, %1, %2"
                    : "=v"(pkB[i]) : "v"(pB[2 * i]), "v"(pB[2 * i + 1]));
            }
            #pragma unroll
            for (int kc = 0; kc < 2; ++kc) {
                unsigned int xa0 = pkA[kc * 4 + 0], ya0 = pkA[kc * 4 + 2];
                unsigned int xa1 = pkA[kc * 4 + 1], ya1 = pkA[kc * 4 + 3];
                unsigned int xb0 = pkB[kc * 4 + 0], yb0 = pkB[kc * 4 + 2];
                unsigned int xb1 = pkB[kc * 4 + 1], yb1 = pkB[kc * 4 + 3];
                asm("v_permlane32_swap_b32 %0, %1" : "+v"(xa0), "+v"(ya0));
                asm("v_permlane32_swap_b32 %0, %1" : "+v"(xa1), "+v"(ya1));
                asm("v_permlane32_swap_b32 %0, %1" : "+v"(xb0), "+v"(yb0));
                asm("v_permlane32_swap_b32 %0, %1" : "+v"(xb1), "+v"(yb1));
                const u32x4 wa = { xa0, xa1, ya0, ya1 };
                const u32x4 wb = { xb0, xb1, yb0, yb1 };
                const bf16x8 paA = __builtin_bit_cast(bf16x8, wa);
                const bf16x8 paB = __builtin_bit_cast(bf16x8, wb);
                #pragma unroll
                for (int dh = 0; dh < 2; ++dh) {
                    oA[dh] = __builtin_amdgcn_mfma_f32_32x32x16_bf16(paA, bv[kc][dh], oA[dh], 0, 0, 0);
                    oB[dh] = __builtin_amdgcn_mfma_f32_32x32x16_bf16(paB, bv[kc][dh], oB[dh], 0, 0, 0);
                }
            }
        } else if (dA) {
            // ---- A only ----
            f32x16 sc = (f32x16)0.0f;
            #pragma unroll
            for (int c = 0; c < 4; ++c)
                sc = __builtin_amdgcn_mfma_f32_32x32x16_bf16(ak[c], aqA[c], sc, 0, 0, 0);
            float p[16];
            #pragma unroll
            for (int r = 0; r < 16; ++r) p[r] = __expf(sc[r] * 0.125f);
            if (klo + 31 > qloA) {                       // diagonal block: causal mask
                #pragma unroll
                for (int r = 0; r < 16; ++r) {
                    const int krow = (r & 3) + 8 * (r >> 2) + 4 * hi;
                    if (klo + krow > qloA + q32) p[r] = 0.0f;
                }
            }
            #pragma unroll
            for (int r = 0; r < 16; ++r) lsA += p[r];
            unsigned int pk[8];
            #pragma unroll
            for (int i = 0; i < 8; ++i)
                asm("v_cvt_pk_bf16_f32 %0, %1, %2"
                    : "=v"(pk[i]) : "v"(p[2 * i]), "v"(p[2 * i + 1]));
            #pragma unroll
            for (int kc = 0; kc < 2; ++kc) {
                unsigned int x0 = pk[kc * 4 + 0], y0 = pk[kc * 4 + 2];
                unsigned int x1 = pk[kc * 4 + 1], y1 = pk[kc * 4 + 3];
                asm("v_permlane32_swap_b32 %0, %1" : "+v"(x0), "+v"(y0));
                asm("v_permlane32_swap_b32 %0, %1" : "+v"(x1), "+v"(y1));
                const u32x4 wv = { x0, x1, y0, y1 };
                const bf16x8 pa = __builtin_bit_cast(bf16x8, wv);
                #pragma unroll
                for (int dh = 0; dh < 2; ++dh)
                    oA[dh] = __builtin_amdgcn_mfma_f32_32x32x16_bf16(pa, bv[kc][dh], oA[dh], 0, 0, 0);
            }
        }
        cur = (cur == 2) ? 0 : cur + 1;
    }

    // ---- epilogue: combine the two k-subtile partials per q-slice, normalize
    float* Obuf = reinterpret_cast<float*>(&Ks[0][0]);   // 2 slots x 8KB (overlay)

    __syncthreads();                           // all compute reads done; overlay safe
    Lt[(wave * 2 + 0) * 64 + lane] = lsA;
    Lt[(wave * 2 + 1) * 64 + lane] = lsB;

    auto writePartial = [&](const f32x16 (&o)[2]) {
        float* slot = Obuf + slice * 2048;
        #pragma unroll
        for (int r = 0; r < 16; ++r) {
            const int row = (r & 3) + 8 * (r >> 2) + 4 * hi;
            #pragma unroll
            for (int dh = 0; dh < 2; ++dh)
                slot[row * 64 + dh * 32 + q32] = o[dh][r];
        }
    };
    auto finalize = [&](int t, int qt, const f32x16 (&o)[2]) {
        const float lf = Lt[(slice * 2 + t) * 64 + q32]
                       + Lt[(slice * 2 + t) * 64 + 32 + q32]
                       + Lt[((slice + 2) * 2 + t) * 64 + q32]
                       + Lt[((slice + 2) * 2 + t) * 64 + 32 + q32];
        const float inv = 1.0f / lf;
        const float* slot = Obuf + slice * 2048;
        #pragma unroll
        for (int r = 0; r < 16; ++r) {
            const int row = (r & 3) + 8 * (r >> 2) + 4 * hi;
            const float invr = __shfl(inv, row);
            const size_t gr = (size_t)(tokBase + qt * 64 + slice * 32 + row) * 1024 + colBase;
            #pragma unroll
            for (int dh = 0; dh < 2; ++dh)
                ctx[gr + dh * 32 + q32] =
                    f2bf((o[dh][r] + slot[row * 64 + dh * 32 + q32]) * invr);
        }
    };

    if (ks == 1) writePartial(oA);             // waves 2,3 publish A partials
    __syncthreads();
    if (ks == 0) finalize(0, qtA, oA);         // waves 0,1 finalize tile A
    __syncthreads();
    if (ks == 0) writePartial(oB);             // waves 0,1 publish B partials
    __syncthreads();
    if (ks == 1) finalize(1, qtB, oB);         // waves 2,3 finalize tile B
}

// ---------------------------------------------------------------------------
extern "C" void kernel_launch(void* const* d_in, const int* in_sizes, int n_in,
                              void* d_out, int out_size, void* d_ws, size_t ws_size,
                              hipStream_t stream)
{
    const float* x  = (const float*)d_in[0];   // [4096,1024] fp32
    const float* Wq = (const float*)d_in[1];
    const float* Wk = (const float*)d_in[2];
    const float* Wv = (const float*)d_in[3];
    const float* Wo = (const float*)d_in[4];
    const float* bo = (const float*)d_in[5];
    float* out = (float*)d_out;

    // ws (32 MB): xb -> ctx after gemm_qkv; kb -> woT after attn.
    // d_out doubles as wqkvT scratch until gemm_op overwrites it.
    unsigned short* xb     = (unsigned short*)d_ws;           // 8 MB -> ctx
    unsigned short* qb     = xb + (size_t)4096 * 1024;        // 8 MB
    unsigned short* kb     = qb + (size_t)4096 * 1024;        // 8 MB -> woT
    unsigned short* vT     = kb + (size_t)4096 * 1024;        // 8 MB [1024][4096]
    unsigned short* ctx    = xb;
    unsigned short* wqkvT  = (unsigned short*)d_out;          // 6.3 MB scratch
    unsigned short* woT    = kb;

    prep<<<2816, 256, 0, stream>>>(x, xb, Wq, Wk, Wv, wqkvT);

    gemm8p<<<dim3(16, 32), 512, 0, stream>>>(xb, wqkvT, qb, kb, vT);

    attn12<<<dim3(16, 32), 256, 0, stream>>>(qb, kb, vT, ctx);

    wconv<<<dim3(16, 16), 256, 0, stream>>>(Wo, woT);

    gemm_op<<<dim3(16, 32), 256, 0, stream>>>(ctx, woT, out, bo);
}